// Round 8
// baseline (181.843 us; speedup 1.0000x reference)
//
#include <hip/hip_runtime.h>
#include <hip/hip_bf16.h>

typedef _Float16 f16;
typedef _Float16 half8 __attribute__((ext_vector_type(8)));
typedef _Float16 half4 __attribute__((ext_vector_type(4)));
typedef float floatx4 __attribute__((ext_vector_type(4)));

#define BM 64
#define NBLK 768
#define NTILE 4096

// ---- ws layout (f16 element offsets) ----
#define WA_OFF 0         // 65536 f16 : WaT frag order (NT=16,KT=8)
#define WB_OFF 65536     // 18432 f16 : WbT (NT=9, KT=4)  nt 0-7=W2, 8=W12
#define WC_OFF 83968     // 2048 f16  : WcT (NT=1, KT=4)  rows 0-3 = W22 cols
#define WF2_OFF 86016    // 4096 f16  : Wf2T [4][NT=2,KT=1]
#define WSF_BYTE_OFF 180224
// wsf (float offsets)
#define BA_OFF 0      // 256: b1 | bf1
#define BB_OFF 256    // 144: b2 | b12
#define BCC_OFF 400   // 4  : b22
#define BF2_OFF 404   // 128: bf2
#define WFIN_OFF 532  // 32
#define BFIN_OFF 564  // 1

__global__ __launch_bounds__(256) void prep_kernel(
    const float* __restrict__ ctx, const float* __restrict__ W1,
    const float* __restrict__ b1, const float* __restrict__ W2,
    const float* __restrict__ b2, const float* __restrict__ W12,
    const float* __restrict__ b12, const float* __restrict__ W22,
    const float* __restrict__ b22, const float* __restrict__ Wf1,
    const float* __restrict__ bf1, const float* __restrict__ Wf2,
    const float* __restrict__ bf2, const float* __restrict__ Wfin,
    const float* __restrict__ bfin, f16* __restrict__ wsh,
    float* __restrict__ wsf)
{
  int tid = blockIdx.x * 256 + threadIdx.x;
  if (tid < 65536) {
    int j = tid & 7, l = (tid >> 3) & 63, kt = (tid >> 9) & 7, nt = tid >> 12;
    int k = kt * 32 + ((l >> 4) << 3) + j, n = nt * 16 + (l & 15);
    float v;
    if (n < 128) v = ctx[k] * W1[k * 128 + n];
    else { int c = n - 128; v = Wf1[((c >> 5) * 256 + k) * 32 + (c & 31)]; }
    wsh[tid] = (f16)v;
  } else if (tid < WB_OFF + 18432) {
    int o = tid - WB_OFF;
    int j = o & 7, l = (o >> 3) & 63, kt = (o >> 9) & 3, nt = o >> 11;
    int k = kt * 32 + ((l >> 4) << 3) + j, n = nt * 16 + (l & 15);
    float v = (n < 128) ? W2[k * 128 + n] : W12[k * 16 + (n - 128)];
    wsh[tid] = (f16)v;
  } else if (tid < WC_OFF + 2048) {
    int o = tid - WC_OFF;
    int j = o & 7, l = (o >> 3) & 63, kt = (o >> 9) & 3;
    int k = kt * 32 + ((l >> 4) << 3) + j, n = l & 15;
    float v = (n < 4) ? W22[k * 4 + n] : 0.f;
    wsh[tid] = (f16)v;
  } else if (tid < WF2_OFF + 4096) {
    int o = tid - WF2_OFF;
    int j = o & 7, l = (o >> 3) & 63, ent = o >> 9;
    int e = ent >> 1, nt = ent & 1;
    int k = ((l >> 4) << 3) + j, n = nt * 16 + (l & 15);
    wsh[tid] = (f16)Wf2[(e * 32 + k) * 32 + n];
  } else if (tid < 90112 + 565) {
    int o = tid - 90112;
    float v;
    if (o < 128) v = b1[o];
    else if (o < 256) v = bf1[o - 128];
    else if (o < 384) v = b2[o - 256];
    else if (o < 400) v = b12[o - 384];
    else if (o < 404) v = b22[o - 400];
    else if (o < 532) v = bf2[o - 404];
    else if (o < 564) v = Wfin[o - 532];
    else v = bfin[0];
    wsf[o] = v;
  }
}

#define MFMA16(A, Bv, C) __builtin_amdgcn_mfma_f32_16x16x32_f16(A, Bv, C, 0, 0, 0)

// LDS map (bytes), 51 KB:
//  G   0..32767     [64][512B] f16 swz : x -> (h | o1) -> (in2 | o1)
//  H2  32768..49151 [64][256B] f16 swz : h2
//  L1  49152..51199 [64][16] f16 logits ; part [64][8] f32 overlays after use
//  C2  51200..52223 [64][4] f32
#define H2_OFF 32768
#define L1_OFF 49152
#define PART_OFF 49152
#define C2_OFF 51200

// (512,2): VGPR cap 128 (empirical hipcc rule cap ~= 256*?/arg2 at 512 thr:
// (512,6)->40+spill, (512,3)->~85). Peak demand here ~105 (32 prefetch live
// through GEMM2-4). Cap 128 avoids the spill trap; occupancy 2 blocks/CU by
// VGPR, compensated by intra-block tile pipelining (prefetch under compute).
__global__ __launch_bounds__(512, 2) void fused_kernel(
    const float* __restrict__ x, const f16* __restrict__ wsh,
    const float* __restrict__ wsf, float* __restrict__ out)
{
  __shared__ __attribute__((aligned(16))) char lds[52224];
  const int t = threadIdx.x;       // 0..511
  const int lane = t & 63;
  const int w = t >> 6;            // 0..7
  const int l15 = lane & 15;
  const int l4 = lane >> 4;
  const int sw = (l15 & 7) << 4;

  float4 nx[8];  // prefetch regs: 8 x float4 = 32 VGPR, static indices only

  int tile = blockIdx.x;
  // prologue: issue loads for first tile
  {
    const float* xb = x + (size_t)tile * BM * 256;
#pragma unroll
    for (int it = 0; it < 4; ++it) {
      int c = it * 512 + t;
      int r = c >> 5;
      int k0 = (c & 31) << 3;
      const float4* xv = (const float4*)(xb + r * 256 + k0);
      nx[it * 2] = xv[0];
      nx[it * 2 + 1] = xv[1];
    }
  }

  while (true) {
    const size_t base = (size_t)tile * BM;

    // ---- stage x tile from prefetch regs -> G (f16, swizzled) ----
#pragma unroll
    for (int it = 0; it < 4; ++it) {
      int c = it * 512 + t;
      int r = c >> 5;
      int k0 = (c & 31) << 3;
      float4 a = nx[it * 2], b = nx[it * 2 + 1];
      half8 hv;
      hv[0] = (f16)a.x; hv[1] = (f16)a.y; hv[2] = (f16)a.z; hv[3] = (f16)a.w;
      hv[4] = (f16)b.x; hv[5] = (f16)b.y; hv[6] = (f16)b.z; hv[7] = (f16)b.w;
      *(half8*)(lds + ((r * 512 + k0 * 2) ^ ((r & 7) << 4))) = hv;
    }
    __syncthreads();  // b0

    // ---- GEMM1: wave w -> n-tiles {2w, 2w+1}; h|o1 overlay x ----
    {
      floatx4 acc[2][4];
#pragma unroll
      for (int q = 0; q < 2; ++q)
#pragma unroll
        for (int mt = 0; mt < 4; ++mt) acc[q][mt] = (floatx4){0.f, 0.f, 0.f, 0.f};
      for (int kt = 0; kt < 8; ++kt) {
        half8 Bx[4];
#pragma unroll
        for (int mt = 0; mt < 4; ++mt) {
          int r = mt * 16 + l15;
          Bx[mt] = *(const half8*)(lds + ((r * 512 + kt * 64 + (l4 << 4)) ^ sw));
        }
#pragma unroll
        for (int q = 0; q < 2; ++q) {
          half8 Wf = *(const half8*)(wsh + WA_OFF + (size_t)(((w * 2 + q) * 8 + kt) * 64 + lane) * 8);
#pragma unroll
          for (int mt = 0; mt < 4; ++mt) acc[q][mt] = MFMA16(Wf, Bx[mt], acc[q][mt]);
        }
      }
      __syncthreads();  // b1: all x reads done before overlay writes
#pragma unroll
      for (int q = 0; q < 2; ++q) {
        int c0 = (w * 2 + q) * 16 + l4 * 4;
        float4 bias = *(const float4*)(wsf + BA_OFF + c0);
#pragma unroll
        for (int mt = 0; mt < 4; ++mt) {
          int r = mt * 16 + l15;
          half4 hv;
#pragma unroll
          for (int i = 0; i < 4; ++i) hv[i] = (f16)fmaxf(acc[q][mt][i] + ((const float*)&bias)[i], 0.f);
          *(half4*)(lds + ((r * 512 + c0 * 2) ^ sw)) = hv;
        }
      }
    }

    // ---- prefetch next tile's x (issue-early; lands during GEMM2..4) ----
    const int next = tile + NBLK;
    const bool has_next = next < NTILE;
    if (has_next) {
      const float* xb = x + (size_t)next * BM * 256;
#pragma unroll
      for (int it = 0; it < 4; ++it) {
        int c = it * 512 + t;
        int r = c >> 5;
        int k0 = (c & 31) << 3;
        const float4* xv = (const float4*)(xb + r * 256 + k0);
        nx[it * 2] = xv[0];
        nx[it * 2 + 1] = xv[1];
      }
    }
    __syncthreads();  // b2

    // ---- GEMM2: wave w -> nt=w (h2 -> H2); wave 7 also nt=8 (L1 logits) ----
    {
      floatx4 acc2[4];
      floatx4 accL[4];
#pragma unroll
      for (int mt = 0; mt < 4; ++mt) {
        acc2[mt] = (floatx4){0.f, 0.f, 0.f, 0.f};
        accL[mt] = (floatx4){0.f, 0.f, 0.f, 0.f};
      }
      for (int kt = 0; kt < 4; ++kt) {
        half8 Bh[4];
#pragma unroll
        for (int mt = 0; mt < 4; ++mt) {
          int r = mt * 16 + l15;
          Bh[mt] = *(const half8*)(lds + ((r * 512 + kt * 64 + (l4 << 4)) ^ sw));
        }
        half8 Wf = *(const half8*)(wsh + WB_OFF + (size_t)((w * 4 + kt) * 64 + lane) * 8);
#pragma unroll
        for (int mt = 0; mt < 4; ++mt) acc2[mt] = MFMA16(Wf, Bh[mt], acc2[mt]);
        if (w == 7) {
          half8 WfL = *(const half8*)(wsh + WB_OFF + (size_t)((32 + kt) * 64 + lane) * 8);
#pragma unroll
          for (int mt = 0; mt < 4; ++mt) accL[mt] = MFMA16(WfL, Bh[mt], accL[mt]);
        }
      }
      // epilogue writes H2 / L1 (fresh regions, disjoint from G reads)
      {
        int c0 = w * 16 + l4 * 4;
        float4 bias = *(const float4*)(wsf + BB_OFF + c0);
#pragma unroll
        for (int mt = 0; mt < 4; ++mt) {
          int r = mt * 16 + l15;
          half4 hv;
#pragma unroll
          for (int i = 0; i < 4; ++i) hv[i] = (f16)fmaxf(acc2[mt][i] + ((const float*)&bias)[i], 0.f);
          *(half4*)(lds + H2_OFF + ((r * 256 + c0 * 2) ^ ((r & 7) << 4))) = hv;
        }
      }
      if (w == 7) {
        float4 biasL = *(const float4*)(wsf + BB_OFF + 128 + l4 * 4);
#pragma unroll
        for (int mt = 0; mt < 4; ++mt) {
          int r = mt * 16 + l15;
          half4 hv;
#pragma unroll
          for (int i = 0; i < 4; ++i) hv[i] = (f16)(accL[mt][i] + ((const float*)&biasL)[i]);
          *(half4*)(lds + L1_OFF + r * 32 + l4 * 8) = hv;
        }
      }
    }
    __syncthreads();  // b3

    // ---- interval b3..b4: GEMM3 (waves 0-3, in-lane c2 -> C2) || softmax+mix ----
    if (w < 4) {
      floatx4 acc3 = (floatx4){0.f, 0.f, 0.f, 0.f};
      int r3 = w * 16 + l15;
#pragma unroll
      for (int kt = 0; kt < 4; ++kt) {
        half8 Bh2 = *(const half8*)(lds + H2_OFF + ((r3 * 256 + kt * 64 + (l4 << 4)) ^ ((r3 & 7) << 4)));
        half8 Wf = *(const half8*)(wsh + WC_OFF + (size_t)(kt * 64 + lane) * 8);
        acc3 = MFMA16(Wf, Bh2, acc3);
      }
      if (lane < 16) {
        float4 bias = *(const float4*)(wsf + BCC_OFF);
        float q0 = acc3[0] + bias.x, q1 = acc3[1] + bias.y;
        float q2 = acc3[2] + bias.z, q3 = acc3[3] + bias.w;
        float m2 = fmaxf(fmaxf(q0, q1), fmaxf(q2, q3));
        float f0 = __expf(q0 - m2), f1 = __expf(q1 - m2);
        float f2 = __expf(q2 - m2), f3 = __expf(q3 - m2);
        float inv2 = 1.f / (f0 + f1 + f2 + f3);
        float4 c2o;
        c2o.x = f0 * inv2; c2o.y = f1 * inv2; c2o.z = f2 * inv2; c2o.w = f3 * inv2;
        *(float4*)(lds + C2_OFF + r3 * 16) = c2o;
      }
    }
    // softmax c1 + mix: in2 overlays DEAD h region, row-sliced per thread
    {
      int r = t >> 3, f = (t >> 1) & 3, hh = t & 1;
      const f16* L1p = (const f16*)(lds + L1_OFF) + r * 16 + f;
      float a0 = (float)L1p[0], a1 = (float)L1p[4], a2 = (float)L1p[8], a3 = (float)L1p[12];
      float m = fmaxf(fmaxf(a0, a1), fmaxf(a2, a3));
      float e0 = __expf(a0 - m), e1 = __expf(a1 - m), e2 = __expf(a2 - m), e3 = __expf(a3 - m);
      float inv = 1.f / (e0 + e1 + e2 + e3);
      f16 c0h = (f16)(e0 * inv), c1h = (f16)(e1 * inv);
      f16 c2h = (f16)(e2 * inv), c3h = (f16)(e3 * inv);
      int swr = (r & 7) << 4;
#pragma unroll
      for (int hi = 0; hi < 2; ++hi) {
        int h8 = hh * 2 + hi;
        half8 o0 = *(const half8*)(lds + ((r * 512 + 256 + 0   + h8 * 16) ^ swr));
        half8 o1v = *(const half8*)(lds + ((r * 512 + 256 + 64  + h8 * 16) ^ swr));
        half8 o2v = *(const half8*)(lds + ((r * 512 + 256 + 128 + h8 * 16) ^ swr));
        half8 o3v = *(const half8*)(lds + ((r * 512 + 256 + 192 + h8 * 16) ^ swr));
        half8 res = o0 * c0h + o1v * c1h + o2v * c2h + o3v * c3h;
        *(half8*)(lds + ((r * 512 + f * 64 + h8 * 16) ^ swr)) = res;
      }
    }
    __syncthreads();  // b4

    // ---- GEMM4: wave w -> expert e = w&3, half ct = w>>2; fused Wfin + c2 ----
    {
      int e = w & 3, ct = w >> 2;
      half8 Wfv = *(const half8*)(wsh + WF2_OFF + (size_t)((e * 2 + ct) * 64 + lane) * 8);
      float4 bv = *(const float4*)(wsf + BF2_OFF + e * 32 + ct * 16 + l4 * 4);
      float4 wfv = *(const float4*)(wsf + WFIN_OFF + ct * 16 + l4 * 4);
      floatx4 a4[4];
#pragma unroll
      for (int mt = 0; mt < 4; ++mt) a4[mt] = (floatx4){0.f, 0.f, 0.f, 0.f};
#pragma unroll
      for (int mt = 0; mt < 4; ++mt) {
        int r = mt * 16 + l15;
        half8 Bi = *(const half8*)(lds + ((r * 512 + e * 64 + (l4 << 4)) ^ ((r & 7) << 4)));
        a4[mt] = MFMA16(Wfv, Bi, a4[mt]);
      }
#pragma unroll
      for (int mt = 0; mt < 4; ++mt) {
        int r = mt * 16 + l15;
        float s = 0.f;
#pragma unroll
        for (int i = 0; i < 4; ++i)
          s += fmaxf(a4[mt][i] + ((const float*)&bv)[i], 0.f) * ((const float*)&wfv)[i];
        s += __shfl_xor(s, 16);
        s += __shfl_xor(s, 32);
        if (l4 == 0) {
          float c2e = *(const float*)(lds + C2_OFF + r * 16 + e * 4);
          *(float*)(lds + PART_OFF + r * 32 + w * 4) = s * c2e;
        }
      }
    }
    __syncthreads();  // b5

    if (t < 64) {
      float4 p0 = *(const float4*)(lds + PART_OFF + t * 32);
      float4 p1 = *(const float4*)(lds + PART_OFF + t * 32 + 16);
      out[base + t] = wsf[BFIN_OFF] + p0.x + p0.y + p0.z + p0.w + p1.x + p1.y + p1.z + p1.w;
    }
    // next L1/PART write only after next b2 -> out-write protected by b0..b2

    if (!has_next) break;
    tile = next;
  }
}

extern "C" void kernel_launch(void* const* d_in, const int* in_sizes, int n_in,
                              void* d_out, int out_size, void* d_ws, size_t ws_size,
                              hipStream_t stream) {
  (void)in_sizes; (void)n_in; (void)ws_size;
  const float* x    = (const float*)d_in[0];
  const float* ctx  = (const float*)d_in[1];
  const float* W1   = (const float*)d_in[2];
  const float* b1   = (const float*)d_in[3];
  const float* W2   = (const float*)d_in[4];
  const float* b2   = (const float*)d_in[5];
  const float* W12  = (const float*)d_in[6];
  const float* b12  = (const float*)d_in[7];
  const float* W22  = (const float*)d_in[8];
  const float* b22  = (const float*)d_in[9];
  const float* Wf1  = (const float*)d_in[10];
  const float* bf1  = (const float*)d_in[11];
  const float* Wf2  = (const float*)d_in[12];
  const float* bf2  = (const float*)d_in[13];
  const float* Wfin = (const float*)d_in[14];
  const float* bfin = (const float*)d_in[15];

  f16* wsh = (f16*)d_ws;
  float* wsf = (float*)((char*)d_ws + WSF_BYTE_OFF);

  prep_kernel<<<355, 256, 0, stream>>>(ctx, W1, b1, W2, b2, W12, b12, W22, b22,
                                       Wf1, bf1, Wf2, bf2, Wfin, bfin, wsh, wsf);

  fused_kernel<<<NBLK, 512, 0, stream>>>(x, wsh, wsf, (float*)d_out);
}

// Round 10
// 102.491 us; speedup vs baseline: 1.7742x; 1.7742x over previous
//
#include <hip/hip_runtime.h>
#include <hip/hip_bf16.h>

typedef _Float16 f16;
typedef _Float16 half8 __attribute__((ext_vector_type(8)));
typedef _Float16 half4 __attribute__((ext_vector_type(4)));
typedef float floatx4 __attribute__((ext_vector_type(4)));

#define BM 64

// ---- ws layout (f16 element offsets) ----
#define WA_OFF 0         // 65536 f16 : WaT frag order (NT=16,KT=8)
#define WB_OFF 65536     // 18432 f16 : WbT (NT=9, KT=4)  nt 0-7=W2, 8=W12
#define WC_OFF 83968     // 2048 f16  : WcT (NT=1, KT=4)  rows 0-3 = W22 cols
#define WF2_OFF 86016    // 4096 f16  : Wf2T [4][NT=2,KT=1]
#define WSF_BYTE_OFF 180224
// wsf (float offsets)
#define BA_OFF 0      // 256: b1 | bf1
#define BB_OFF 256    // 144: b2 | b12
#define BCC_OFF 400   // 4  : b22
#define BF2_OFF 404   // 128: bf2
#define WFIN_OFF 532  // 32
#define BFIN_OFF 564  // 1

__global__ __launch_bounds__(256) void prep_kernel(
    const float* __restrict__ ctx, const float* __restrict__ W1,
    const float* __restrict__ b1, const float* __restrict__ W2,
    const float* __restrict__ b2, const float* __restrict__ W12,
    const float* __restrict__ b12, const float* __restrict__ W22,
    const float* __restrict__ b22, const float* __restrict__ Wf1,
    const float* __restrict__ bf1, const float* __restrict__ Wf2,
    const float* __restrict__ bf2, const float* __restrict__ Wfin,
    const float* __restrict__ bfin, f16* __restrict__ wsh,
    float* __restrict__ wsf)
{
  int tid = blockIdx.x * 256 + threadIdx.x;
  if (tid < 65536) {
    int j = tid & 7, l = (tid >> 3) & 63, kt = (tid >> 9) & 7, nt = tid >> 12;
    int k = kt * 32 + ((l >> 4) << 3) + j, n = nt * 16 + (l & 15);
    float v;
    if (n < 128) v = ctx[k] * W1[k * 128 + n];
    else { int c = n - 128; v = Wf1[((c >> 5) * 256 + k) * 32 + (c & 31)]; }
    wsh[tid] = (f16)v;
  } else if (tid < WB_OFF + 18432) {
    int o = tid - WB_OFF;
    int j = o & 7, l = (o >> 3) & 63, kt = (o >> 9) & 3, nt = o >> 11;
    int k = kt * 32 + ((l >> 4) << 3) + j, n = nt * 16 + (l & 15);
    float v = (n < 128) ? W2[k * 128 + n] : W12[k * 16 + (n - 128)];
    wsh[tid] = (f16)v;
  } else if (tid < WC_OFF + 2048) {
    int o = tid - WC_OFF;
    int j = o & 7, l = (o >> 3) & 63, kt = (o >> 9) & 3;
    int k = kt * 32 + ((l >> 4) << 3) + j, n = l & 15;
    float v = (n < 4) ? W22[k * 4 + n] : 0.f;
    wsh[tid] = (f16)v;
  } else if (tid < WF2_OFF + 4096) {
    int o = tid - WF2_OFF;
    int j = o & 7, l = (o >> 3) & 63, ent = o >> 9;
    int e = ent >> 1, nt = ent & 1;
    int k = ((l >> 4) << 3) + j, n = nt * 16 + (l & 15);
    wsh[tid] = (f16)Wf2[(e * 32 + k) * 32 + n];
  } else if (tid < 90112 + 565) {
    int o = tid - 90112;
    float v;
    if (o < 128) v = b1[o];
    else if (o < 256) v = bf1[o - 128];
    else if (o < 384) v = b2[o - 256];
    else if (o < 400) v = b12[o - 384];
    else if (o < 404) v = b22[o - 400];
    else if (o < 532) v = bf2[o - 404];
    else if (o < 564) v = Wfin[o - 532];
    else v = bfin[0];
    wsf[o] = v;
  }
}

#define MFMA16(A, Bv, C) __builtin_amdgcn_mfma_f32_16x16x32_f16(A, Bv, C, 0, 0, 0)

// Fragment-major LDS: a [64 rows][K] f16 activation = frags of 1 KB, frag =
// mt*KT + kt (row-tile mt=row>>4, k-tile kt=k>>5). Element (lane,j) of a frag
// sits at frag*1024 + lane*16 + j*2, XOR-swizzled so BOTH the wave-level
// b128 frag reads AND the scattered staging/epilogue writes are bank-spread.
__device__ __forceinline__ int fragaddr(int frag, int lanep) {
  return frag * 1024 + ((lanep * 16) ^ (((lanep >> 3) & 7) << 4) ^ ((frag & 7) << 4));
}

// LDS map (bytes), 51 KB -> 3 blocks/CU (256 thr, 4 waves):
//  G    0..32767  : x frags 0..31 ; then h frags 0..15 (base 0, 16 KB)
//                   and o1 frags 0..15 (base 16384); in2 overlays dead h.
//  H2   32768..49151 : h2 frags 0..15
//  L1   49152..51199 : [64][16] f16 logits ; PART [64][4] f32 overlays after
//  C2   51200..52223 : [64][4] f32
#define O1_OFF 16384
#define H2_OFF 32768
#define L1_OFF 49152
#define PART_OFF 49152
#define C2_OFF 51200

__global__ __launch_bounds__(256, 2) void fused_kernel(
    const float* __restrict__ x, const f16* __restrict__ wsh,
    const float* __restrict__ wsf, float* __restrict__ out)
{
  __shared__ __attribute__((aligned(16))) char lds[52224];
  const int t = threadIdx.x;
  const int lane = t & 63;
  const int w = t >> 6;
  const int l15 = lane & 15;
  const int l4 = lane >> 4;
  const size_t base = (size_t)blockIdx.x * BM;
  const floatx4 zero4 = {0.f, 0.f, 0.f, 0.f};

  // ---- stage x -> f16 frag-major ----
#pragma unroll
  for (int it = 0; it < 8; ++it) {
    int c = it * 256 + t;
    int r = c >> 5;
    int k0 = (c & 31) << 3;  // f32 index, multiple of 8
    const float4* xv = (const float4*)(x + (base + (size_t)r) * 256 + k0);
    float4 a = xv[0], b = xv[1];
    half8 hv;
    hv[0] = (f16)a.x; hv[1] = (f16)a.y; hv[2] = (f16)a.z; hv[3] = (f16)a.w;
    hv[4] = (f16)b.x; hv[5] = (f16)b.y; hv[6] = (f16)b.z; hv[7] = (f16)b.w;
    int frag = (r >> 4) * 8 + (k0 >> 5);
    int lanep = (r & 15) + (((k0 >> 3) & 3) << 4);
    *(half8*)(lds + fragaddr(frag, lanep)) = hv;
  }
  __syncthreads();  // b0

  // ---- GEMM1: wave w -> n-tiles w*4..w*4+3 ----
  {
    floatx4 acc[4][4];
#pragma unroll
    for (int q = 0; q < 4; ++q)
#pragma unroll
      for (int mt = 0; mt < 4; ++mt) acc[q][mt] = zero4;
    for (int kt = 0; kt < 8; ++kt) {
      half8 Bx[4];
#pragma unroll
      for (int mt = 0; mt < 4; ++mt)
        Bx[mt] = *(const half8*)(lds + fragaddr(mt * 8 + kt, lane));
#pragma unroll
      for (int q = 0; q < 4; ++q) {
        half8 Wf = *(const half8*)(wsh + WA_OFF + (size_t)(((w * 4 + q) * 8 + kt) * 64 + lane) * 8);
#pragma unroll
        for (int mt = 0; mt < 4; ++mt) acc[q][mt] = MFMA16(Wf, Bx[mt], acc[q][mt]);
      }
    }
    __syncthreads();  // b1: x reads done before h|o1 overlay writes
#pragma unroll
    for (int q = 0; q < 4; ++q) {
      int n0 = (w * 4 + q) * 16;           // tile base col (wave-uniform)
      int n = n0 + l4 * 4;                  // this lane's 4 cols
      float4 bias = *(const float4*)(wsf + BA_OFF + n);
      int j0 = (l4 * 4) & 7;
      int v4 = (n >> 3) & 3;
#pragma unroll
      for (int mt = 0; mt < 4; ++mt) {
        half4 hv;
#pragma unroll
        for (int i = 0; i < 4; ++i) hv[i] = (f16)fmaxf(acc[q][mt][i] + ((const float*)&bias)[i], 0.f);
        int lanep = l15 + (v4 << 4);
        int addr;
        if (n0 < 128) addr = fragaddr(mt * 4 + (n0 >> 5), lanep);                 // h
        else addr = O1_OFF + fragaddr(((n0 - 128) >> 5) * 4 + mt, lanep);         // o1 (frag=e*4+mt)
        *(half4*)(lds + addr + j0 * 2) = hv;
      }
    }
  }
  __syncthreads();  // b2

  // ---- GEMM2: wave w -> nt2 = w*2+{0,1}; wave 3 also nt=8 (L1 logits) ----
  {
    floatx4 acc2[2][4];
    floatx4 accL[4];
#pragma unroll
    for (int q = 0; q < 2; ++q)
#pragma unroll
      for (int mt = 0; mt < 4; ++mt) acc2[q][mt] = zero4;
#pragma unroll
    for (int mt = 0; mt < 4; ++mt) accL[mt] = zero4;
    for (int kt = 0; kt < 4; ++kt) {
      half8 Bh[4];
#pragma unroll
      for (int mt = 0; mt < 4; ++mt)
        Bh[mt] = *(const half8*)(lds + fragaddr(mt * 4 + kt, lane));
#pragma unroll
      for (int q = 0; q < 2; ++q) {
        half8 Wf = *(const half8*)(wsh + WB_OFF + (size_t)(((w * 2 + q) * 4 + kt) * 64 + lane) * 8);
#pragma unroll
        for (int mt = 0; mt < 4; ++mt) acc2[q][mt] = MFMA16(Wf, Bh[mt], acc2[q][mt]);
      }
      if (w == 3) {
        half8 WfL = *(const half8*)(wsh + WB_OFF + (size_t)((32 + kt) * 64 + lane) * 8);
#pragma unroll
        for (int mt = 0; mt < 4; ++mt) accL[mt] = MFMA16(WfL, Bh[mt], accL[mt]);
      }
    }
    // epilogue: writes H2 (fresh) and L1 (fresh) — no pre-barrier needed
#pragma unroll
    for (int q = 0; q < 2; ++q) {
      int n0 = (w * 2 + q) * 16;
      int n = n0 + l4 * 4;
      float4 bias = *(const float4*)(wsf + BB_OFF + n);
      int j0 = (l4 * 4) & 7;
      int v4 = (n >> 3) & 3;
#pragma unroll
      for (int mt = 0; mt < 4; ++mt) {
        half4 hv;
#pragma unroll
        for (int i = 0; i < 4; ++i) hv[i] = (f16)fmaxf(acc2[q][mt][i] + ((const float*)&bias)[i], 0.f);
        *(half4*)(lds + H2_OFF + fragaddr(mt * 4 + (n0 >> 5), l15 + (v4 << 4)) + j0 * 2) = hv;
      }
    }
    if (w == 3) {
      float4 biasL = *(const float4*)(wsf + BB_OFF + 128 + l4 * 4);
#pragma unroll
      for (int mt = 0; mt < 4; ++mt) {
        half4 hv;
#pragma unroll
        for (int i = 0; i < 4; ++i) hv[i] = (f16)(accL[mt][i] + ((const float*)&biasL)[i]);
        *(half4*)(lds + L1_OFF + (mt * 16 + l15) * 32 + l4 * 8) = hv;
      }
    }
  }
  __syncthreads();  // b3

  // ---- interval b3..b4: GEMM3 (wave w -> mt=w; in-lane c2) then softmax+mix ----
  {
    floatx4 acc3 = zero4;
#pragma unroll
    for (int kt = 0; kt < 4; ++kt) {
      half8 Bh2 = *(const half8*)(lds + H2_OFF + fragaddr(w * 4 + kt, lane));
      half8 Wf = *(const half8*)(wsh + WC_OFF + (size_t)(kt * 64 + lane) * 8);
      acc3 = MFMA16(Wf, Bh2, acc3);
    }
    if (l4 == 0) {
      float4 bias = *(const float4*)(wsf + BCC_OFF);
      float q0 = acc3[0] + bias.x, q1 = acc3[1] + bias.y;
      float q2 = acc3[2] + bias.z, q3 = acc3[3] + bias.w;
      float m2 = fmaxf(fmaxf(q0, q1), fmaxf(q2, q3));
      float f0 = __expf(q0 - m2), f1 = __expf(q1 - m2);
      float f2 = __expf(q2 - m2), f3 = __expf(q3 - m2);
      float inv2 = 1.f / (f0 + f1 + f2 + f3);
      float4 c2o;
      c2o.x = f0 * inv2; c2o.y = f1 * inv2; c2o.z = f2 * inv2; c2o.w = f3 * inv2;
      *(float4*)(lds + C2_OFF + (w * 16 + l15) * 16) = c2o;
    }
  }
  // softmax c1 + mix: thread (r = t>>2, f = t&3); in2 overlays DEAD h frags
  {
    int r = t >> 2, f = t & 3;
    const f16* L1p = (const f16*)(lds + L1_OFF) + r * 16 + f;
    float a0 = (float)L1p[0], a1 = (float)L1p[4], a2 = (float)L1p[8], a3 = (float)L1p[12];
    float m = fmaxf(fmaxf(a0, a1), fmaxf(a2, a3));
    float e0 = __expf(a0 - m), e1 = __expf(a1 - m), e2 = __expf(a2 - m), e3 = __expf(a3 - m);
    float inv = 1.f / (e0 + e1 + e2 + e3);
    f16 c0h = (f16)(e0 * inv), c1h = (f16)(e1 * inv);
    f16 c2h = (f16)(e2 * inv), c3h = (f16)(e3 * inv);
    int mt = r >> 4;
    int r15 = r & 15;
#pragma unroll
    for (int h8 = 0; h8 < 4; ++h8) {
      int lanep = r15 + (h8 << 4);
      half8 o0 = *(const half8*)(lds + O1_OFF + fragaddr(0 * 4 + mt, lanep));
      half8 o1v = *(const half8*)(lds + O1_OFF + fragaddr(1 * 4 + mt, lanep));
      half8 o2v = *(const half8*)(lds + O1_OFF + fragaddr(2 * 4 + mt, lanep));
      half8 o3v = *(const half8*)(lds + O1_OFF + fragaddr(3 * 4 + mt, lanep));
      half8 res = o0 * c0h + o1v * c1h + o2v * c2h + o3v * c3h;
      *(half8*)(lds + fragaddr(f * 4 + mt, lanep)) = res;  // in2 over dead h
    }
  }
  __syncthreads();  // b4

  // ---- GEMM4: wave w = expert e; fused Wfin + c2 reduce ----
  {
    half8 Bi[4];
#pragma unroll
    for (int mt = 0; mt < 4; ++mt)
      Bi[mt] = *(const half8*)(lds + fragaddr(w * 4 + mt, lane));  // in2 frag f=w
    floatx4 acc4[2][4];
#pragma unroll
    for (int ct = 0; ct < 2; ++ct) {
      half8 Wfv = *(const half8*)(wsh + WF2_OFF + (size_t)((w * 2 + ct) * 64 + lane) * 8);
#pragma unroll
      for (int mt = 0; mt < 4; ++mt) {
        floatx4 z = zero4;
        acc4[ct][mt] = MFMA16(Wfv, Bi[mt], z);
      }
    }
    float4 b0 = *(const float4*)(wsf + BF2_OFF + w * 32 + l4 * 4);
    float4 b1 = *(const float4*)(wsf + BF2_OFF + w * 32 + 16 + l4 * 4);
    float4 wf0 = *(const float4*)(wsf + WFIN_OFF + l4 * 4);
    float4 wf1 = *(const float4*)(wsf + WFIN_OFF + 16 + l4 * 4);
#pragma unroll
    for (int mt = 0; mt < 4; ++mt) {
      int r = mt * 16 + l15;
      float s = 0.f;
#pragma unroll
      for (int i = 0; i < 4; ++i) {
        s += fmaxf(acc4[0][mt][i] + ((const float*)&b0)[i], 0.f) * ((const float*)&wf0)[i];
        s += fmaxf(acc4[1][mt][i] + ((const float*)&b1)[i], 0.f) * ((const float*)&wf1)[i];
      }
      s += __shfl_xor(s, 16);
      s += __shfl_xor(s, 32);
      if (l4 == 0) {
        float c2e = *(const float*)(lds + C2_OFF + r * 16 + w * 4);
        *(float*)(lds + PART_OFF + r * 16 + w * 4) = s * c2e;
      }
    }
  }
  __syncthreads();  // b5

  if (t < 64) {
    float4 p = *(const float4*)(lds + PART_OFF + t * 16);
    out[base + t] = wsf[BFIN_OFF] + p.x + p.y + p.z + p.w;
  }
}

extern "C" void kernel_launch(void* const* d_in, const int* in_sizes, int n_in,
                              void* d_out, int out_size, void* d_ws, size_t ws_size,
                              hipStream_t stream) {
  (void)in_sizes; (void)n_in; (void)ws_size;
  const float* x    = (const float*)d_in[0];
  const float* ctx  = (const float*)d_in[1];
  const float* W1   = (const float*)d_in[2];
  const float* b1   = (const float*)d_in[3];
  const float* W2   = (const float*)d_in[4];
  const float* b2   = (const float*)d_in[5];
  const float* W12  = (const float*)d_in[6];
  const float* b12  = (const float*)d_in[7];
  const float* W22  = (const float*)d_in[8];
  const float* b22  = (const float*)d_in[9];
  const float* Wf1  = (const float*)d_in[10];
  const float* bf1  = (const float*)d_in[11];
  const float* Wf2  = (const float*)d_in[12];
  const float* bf2  = (const float*)d_in[13];
  const float* Wfin = (const float*)d_in[14];
  const float* bfin = (const float*)d_in[15];

  f16* wsh = (f16*)d_ws;
  float* wsf = (float*)((char*)d_ws + WSF_BYTE_OFF);

  prep_kernel<<<355, 256, 0, stream>>>(ctx, W1, b1, W2, b2, W12, b12, W22, b22,
                                       Wf1, bf1, Wf2, bf2, Wfin, bfin, wsh, wsf);

  int nblocks = 262144 / BM;  // 4096
  fused_kernel<<<nblocks, 256, 0, stream>>>(x, wsh, wsf, (float*)d_out);
}